// Round 11
// baseline (114.465 us; speedup 1.0000x reference)
//
#include <hip/hip_runtime.h>
#include <hip/hip_bf16.h>

#define B_ 4096
#define G_ 8
#define IN_ 512
#define H_ 1024
#define OUT_ 64
#define MAXT64 72   // max 64-row tiles: 4096/64 + 8
#define MAXT32 136  // max 32-row tiles: 4096/32 + 8

typedef float f32x4 __attribute__((ext_vector_type(4)));
typedef __bf16 bf16x8 __attribute__((ext_vector_type(8)));
typedef unsigned short u16x8 __attribute__((ext_vector_type(8)));

__device__ inline unsigned short f2bf(float f) {
  unsigned int u = __builtin_bit_cast(unsigned int, f);
  u += 0x7fffu + ((u >> 16) & 1u);
  return (unsigned short)(u >> 16);
}

__device__ inline u16x8 pack8(float4 a, float4 b) {
  return u16x8{f2bf(a.x), f2bf(a.y), f2bf(a.z), f2bf(a.w),
               f2bf(b.x), f2bf(b.y), f2bf(b.z), f2bf(b.w)};
}

// Tile lookup for row-tile size 2^shift.
__device__ inline bool tile_lookup(const int* __restrict__ meta, int mt,
                                   int shift, int& g, int& row0, int& start,
                                   int& cnt) {
  int ts = 0;
  bool found = false;
#pragma unroll
  for (int gg = 0; gg < G_; gg++) {
    int s = meta[gg], e = meta[gg + 1];
    int T = (e - s + (1 << shift) - 1) >> shift;
    if (!found && mt >= ts && mt < ts + T) {
      g = gg;
      row0 = (mt - ts) << shift;
      start = s;
      cnt = e - s;
      found = true;
    }
    ts += T;
  }
  return found;
}

// ---------------------------------------------------------------------------
// prep (fused, all blocks independent):
//   [0,4096):    W1 [G][IN][H] f32 -> W1t [G][H][IN] bf16
//   [4096,4608): W2 [G][H][OUT] f32 -> W2t [G][OUT][H] bf16
//   [4608,5632): x f32 -> xb bf16
//   5632:        deterministic stable bucket (no atomics)
// ---------------------------------------------------------------------------
__global__ __launch_bounds__(256) void prep_kernel(
    const float* __restrict__ W1, const float* __restrict__ W2,
    const float* __restrict__ x, const int* __restrict__ gid,
    unsigned short* __restrict__ W1t, unsigned short* __restrict__ W2t,
    unsigned short* __restrict__ xb, int* __restrict__ meta,
    int* __restrict__ perm) {
  int b = blockIdx.x;
  int t = threadIdx.x;
  if (b < 4096) {
    __shared__ float tile[32][33];
    int h32 = b & 31, k32 = (b >> 5) & 15, g = b >> 9;
    int kl = t >> 3, nl = (t & 7) * 4;
    const float* src =
        W1 + ((size_t)g * IN_ + k32 * 32 + kl) * H_ + h32 * 32 + nl;
    float4 v = *(const float4*)src;
    tile[kl][nl + 0] = v.x;
    tile[kl][nl + 1] = v.y;
    tile[kl][nl + 2] = v.z;
    tile[kl][nl + 3] = v.w;
    __syncthreads();
    int nl2 = t >> 3, kl2 = (t & 7) * 4;
    ushort4 o;
    o.x = f2bf(tile[kl2 + 0][nl2]);
    o.y = f2bf(tile[kl2 + 1][nl2]);
    o.z = f2bf(tile[kl2 + 2][nl2]);
    o.w = f2bf(tile[kl2 + 3][nl2]);
    *(ushort4*)(W1t + ((size_t)g * H_ + h32 * 32 + nl2) * IN_ + k32 * 32 +
                kl2) = o;
  } else if (b < 4608) {
    __shared__ float tile2[32][33];
    int bb = b - 4096;
    int g = bb >> 6, k32 = (bb >> 1) & 31, n32 = bb & 1;
    int kl = t >> 3, nl = (t & 7) * 4;
    const float* src =
        W2 + ((size_t)g * H_ + k32 * 32 + kl) * OUT_ + n32 * 32 + nl;
    float4 v = *(const float4*)src;
    tile2[kl][nl + 0] = v.x;
    tile2[kl][nl + 1] = v.y;
    tile2[kl][nl + 2] = v.z;
    tile2[kl][nl + 3] = v.w;
    __syncthreads();
    int nl2 = t >> 3, kl2 = (t & 7) * 4;
    ushort4 o;
    o.x = f2bf(tile2[kl2 + 0][nl2]);
    o.y = f2bf(tile2[kl2 + 1][nl2]);
    o.z = f2bf(tile2[kl2 + 2][nl2]);
    o.w = f2bf(tile2[kl2 + 3][nl2]);
    *(ushort4*)(W2t + ((size_t)g * OUT_ + n32 * 32 + nl2) * H_ + k32 * 32 +
                kl2) = o;
  } else if (b < 5632) {
    int bb = b - 4608;
    size_t base = (size_t)bb * 2048 + t * 8;
    float4 v0 = *(const float4*)(x + base);
    float4 v1 = *(const float4*)(x + base + 4);
    *(u16x8*)(xb + base) = pack8(v0, v1);
  } else {
    __shared__ unsigned short lc[G_][256];
    __shared__ int offs_s[G_ + 1];
#pragma unroll
    for (int g = 0; g < G_; g++) lc[g][t] = 0;
    int myg[16];
    const int base = t * 16;
    __syncthreads();
#pragma unroll
    for (int j = 0; j < 16; j++) {
      myg[j] = gid[base + j];
      lc[myg[j]][t]++;
    }
    __syncthreads();
    {
      int g = t >> 5, k = t & 31;
      unsigned short pref[8];
      int s = 0;
#pragma unroll
      for (int j = 0; j < 8; j++) {
        pref[j] = (unsigned short)s;
        s += lc[g][8 * k + j];
      }
      int incl = s;
#pragma unroll
      for (int d = 1; d < 32; d <<= 1) {
        int o = __shfl_up(incl, d, 32);
        if (k >= d) incl += o;
      }
      int excl = incl - s;
      if (k == 31) offs_s[g + 1] = incl;
#pragma unroll
      for (int j = 0; j < 8; j++)
        lc[g][8 * k + j] = (unsigned short)(excl + pref[j]);
    }
    __syncthreads();
    if (t == 0) {
      int o = 0;
      for (int g = 0; g < G_; g++) {
        int c = offs_s[g + 1];
        offs_s[g] = o;
        meta[g] = o;
        o += c;
      }
      offs_s[G_] = o;
      meta[G_] = o;
    }
    __syncthreads();
    int cur[G_];
#pragma unroll
    for (int g = 0; g < G_; g++) cur[g] = offs_s[g] + (int)lc[g][t];
#pragma unroll
    for (int j = 0; j < 16; j++) {
      int g = myg[j];
      perm[cur[g]++] = base + j;
    }
  }
}

// ---------------------------------------------------------------------------
// gemm1: hb[start+r][:] = relu(xb[perm]·W1t[g] + b1[g]), bf16, permuted rows.
// 32x64 tile, BK=128 -> 4 iters (HALF the barriers of R9). Double-buffered
// LDS (48 KB total, 3 blocks/CU), 1 barrier/iter, loads issued one iteration
// ahead. 128-wide chunk-XOR swizzle c^(r&7) (gemm2-proven).
// ---------------------------------------------------------------------------
__global__ __launch_bounds__(256) void gemm1_kernel(
    const unsigned short* __restrict__ xb,
    const unsigned short* __restrict__ W1t, const float* __restrict__ b1,
    const int* __restrict__ meta, const int* __restrict__ perm,
    unsigned short* __restrict__ hb) {
  int b = blockIdx.x;
  int mt = b >> 4, nt = b & 15;
  int g, row0, start, cnt;
  if (!tile_lookup(meta, mt, 5, g, row0, start, cnt)) return;
  int n0 = nt * 64;

  __shared__ __attribute__((aligned(16))) unsigned short As[2][32 * 128];
  __shared__ __attribute__((aligned(16))) unsigned short Bs[2][64 * 128];
  __shared__ int rows[32];

  int tid = threadIdx.x;
  int lane = tid & 63;
  int wv = tid >> 6;

  if (tid < 32) rows[tid] = perm[start + min(row0 + tid, cnt - 1)];
  __syncthreads();

  // A staging: thread t -> row r=t>>3, chunk pair 2c,2c+1 (c=t&7), 32 B/iter
  int r = tid >> 3, c2 = (tid & 7) * 2;
  const unsigned short* xsrc = xb + (size_t)rows[r] * IN_;
  int asl0 = c2 ^ (r & 7);        // swizzled slot of chunk c2
  int asl1 = (c2 + 1) ^ (r & 7);  // swizzled slot of chunk c2+1
  int aoff0 = r * 128 + (asl0 << 3);
  int aoff1 = r * 128 + (asl1 << 3);

  // B staging (gemm2-proven): thread t -> row bn=t>>2, chunks 4qd..4qd+3
  int bn = tid >> 2, qd = tid & 3;
  const unsigned short* bsrc =
      W1t + ((size_t)g * H_ + n0 + bn) * IN_ + qd * 32;
  int bdst[4];
#pragma unroll
  for (int j = 0; j < 4; j++) {
    int ch = 4 * qd + j;
    bdst[j] = bn * 128 + (((ch ^ (bn & 7)) & 15) << 3);
  }

  // fragments: wave tile 16x32 (m-quarter x n-half), 128-elem LDS rows
  int fl = lane & 15, q = lane >> 4;
  int m0 = (wv >> 1) * 16, nw = (wv & 1) * 32;
  int apA = (m0 + fl) * 128;
  int bpA = (nw + fl) * 128;
  int bpB = (nw + 16 + fl) * 128;

  f32x4 acc[2];
  acc[0] = f32x4{0.f, 0.f, 0.f, 0.f};
  acc[1] = f32x4{0.f, 0.f, 0.f, 0.f};

  // prologue: L0 -> buf0; issue L1
  u16x8 a0r = *(const u16x8*)(xsrc + c2 * 8);
  u16x8 a1r = *(const u16x8*)(xsrc + c2 * 8 + 8);
  u16x8 bv[4];
#pragma unroll
  for (int j = 0; j < 4; j++) bv[j] = *(const u16x8*)(bsrc + j * 8);
  *(u16x8*)&As[0][aoff0] = a0r;
  *(u16x8*)&As[0][aoff1] = a1r;
#pragma unroll
  for (int j = 0; j < 4; j++) *(u16x8*)&Bs[0][bdst[j]] = bv[j];
  a0r = *(const u16x8*)(xsrc + 128 + c2 * 8);
  a1r = *(const u16x8*)(xsrc + 128 + c2 * 8 + 8);
#pragma unroll
  for (int j = 0; j < 4; j++) bv[j] = *(const u16x8*)(bsrc + 128 + j * 8);
  __syncthreads();  // buf0 visible; L1 loads in flight

  for (int it = 0; it < 4; it++) {
    int p = it & 1;
    if (it < 3) {  // commit L_{it+1} regs to the other buffer
      *(u16x8*)&As[p ^ 1][aoff0] = a0r;
      *(u16x8*)&As[p ^ 1][aoff1] = a1r;
#pragma unroll
      for (int j = 0; j < 4; j++) *(u16x8*)&Bs[p ^ 1][bdst[j]] = bv[j];
    }
    if (it < 2) {  // issue L_{it+2}
      int kn = (it + 2) * 128;
      a0r = *(const u16x8*)(xsrc + kn + c2 * 8);
      a1r = *(const u16x8*)(xsrc + kn + c2 * 8 + 8);
#pragma unroll
      for (int j = 0; j < 4; j++)
        bv[j] = *(const u16x8*)(bsrc + kn + j * 8);
    }
#pragma unroll
    for (int s = 0; s < 4; s++) {
      int off = (((s << 2) + q) ^ (fl & 7)) << 3;
      bf16x8 a = *(const bf16x8*)&As[p][apA + off];
      bf16x8 fb0 = *(const bf16x8*)&Bs[p][bpA + off];
      bf16x8 fb1 = *(const bf16x8*)&Bs[p][bpB + off];
      acc[0] = __builtin_amdgcn_mfma_f32_16x16x32_bf16(a, fb0, acc[0], 0, 0, 0);
      acc[1] = __builtin_amdgcn_mfma_f32_16x16x32_bf16(a, fb1, acc[1], 0, 0, 0);
    }
    __syncthreads();  // one barrier/iter (4 total)
  }

#pragma unroll
  for (int ni = 0; ni < 2; ni++) {
    int col = n0 + nw + ni * 16 + fl;
    float bias = b1[g * H_ + col];
#pragma unroll
    for (int rg = 0; rg < 4; rg++) {
      int rl = m0 + q * 4 + rg;
      if (row0 + rl < cnt) {
        float v = fmaxf(acc[ni][rg] + bias, 0.f);
        hb[(size_t)(start + row0 + rl) * H_ + col] = f2bf(v);
      }
    }
  }
}

// ---------------------------------------------------------------------------
// gemm2: y[perm[r]] = hb[r]·W2t[g] + b2[g]. Full K=1024 (8 iters of BK=128),
// plain stores, deterministic, double-buffered (round-7 proven).
// ---------------------------------------------------------------------------
__global__ __launch_bounds__(256) void gemm2_kernel(
    const unsigned short* __restrict__ hb,
    const unsigned short* __restrict__ W2t, const float* __restrict__ b2,
    const int* __restrict__ meta, const int* __restrict__ perm,
    float* __restrict__ y) {
  int mt = blockIdx.x;
  int g, row0, start, cnt;
  if (!tile_lookup(meta, mt, 6, g, row0, start, cnt)) return;

  __shared__ __attribute__((aligned(16))) unsigned short As2[2][64 * 128];
  __shared__ __attribute__((aligned(16))) unsigned short Bs2[2][64 * 128];
  __shared__ int rows[64];

  int tid = threadIdx.x;
  int lane = tid & 63;
  int wv = tid >> 6;

  if (tid < 64) rows[tid] = perm[start + min(row0 + tid, cnt - 1)];

  int arow_in_op = lane >> 4;
  int asl = lane & 15;
  const unsigned short* asrc[4];
  int adst[4];
#pragma unroll
  for (int j = 0; j < 4; j++) {
    int row = wv * 16 + j * 4 + arow_in_op;
    int cs = asl ^ (row & 7);
    asrc[j] =
        hb + (size_t)(start + min(row0 + row, cnt - 1)) * H_ + (cs << 3);
    adst[j] = (wv * 16 + j * 4) * 128 + lane * 8;
  }

  int bn = tid >> 2, qd = tid & 3;
  const unsigned short* bsrc = W2t + ((size_t)g * OUT_ + bn) * H_ + qd * 32;
  int bdst[4];
#pragma unroll
  for (int j = 0; j < 4; j++) {
    int ch = 4 * qd + j;
    bdst[j] = bn * 128 + ((ch ^ (bn & 7)) << 3);
  }

  int fl = lane & 15, q = lane >> 4;
  int m0 = (wv >> 1) * 32, nw = (wv & 1) * 32;
  int apA = (m0 + fl) * 128;
  int apB = (m0 + 16 + fl) * 128;
  int bpA = (nw + fl) * 128;
  int bpB = (nw + 16 + fl) * 128;

  f32x4 acc[2][2];
#pragma unroll
  for (int i = 0; i < 2; i++)
#pragma unroll
    for (int j = 0; j < 2; j++) acc[i][j] = f32x4{0.f, 0.f, 0.f, 0.f};

  u16x8 av[4], bv[4];
#pragma unroll
  for (int j = 0; j < 4; j++) av[j] = *(const u16x8*)(asrc[j] + 0);
#pragma unroll
  for (int j = 0; j < 4; j++) bv[j] = *(const u16x8*)(bsrc + j * 8);
  __syncthreads();  // rows[] visible
#pragma unroll
  for (int j = 0; j < 4; j++) *(u16x8*)&As2[0][adst[j]] = av[j];
#pragma unroll
  for (int j = 0; j < 4; j++) *(u16x8*)&Bs2[0][bdst[j]] = bv[j];
#pragma unroll
  for (int j = 0; j < 4; j++) av[j] = *(const u16x8*)(asrc[j] + 128);
#pragma unroll
  for (int j = 0; j < 4; j++) bv[j] = *(const u16x8*)(bsrc + 128 + j * 8);
  __syncthreads();

  for (int it = 0; it < 8; it++) {
    int p = it & 1;
    if (it < 7) {
#pragma unroll
      for (int j = 0; j < 4; j++) *(u16x8*)&As2[p ^ 1][adst[j]] = av[j];
#pragma unroll
      for (int j = 0; j < 4; j++) *(u16x8*)&Bs2[p ^ 1][bdst[j]] = bv[j];
    }
    if (it < 6) {
      int kn = (it + 2) * 128;
#pragma unroll
      for (int j = 0; j < 4; j++) av[j] = *(const u16x8*)(asrc[j] + kn);
#pragma unroll
      for (int j = 0; j < 4; j++)
        bv[j] = *(const u16x8*)(bsrc + kn + j * 8);
    }
#pragma unroll
    for (int s = 0; s < 4; s++) {
      int off = (((s << 2) + q) ^ (fl & 7)) << 3;
      bf16x8 a0 = *(const bf16x8*)&As2[p][apA + off];
      bf16x8 a1 = *(const bf16x8*)&As2[p][apB + off];
      bf16x8 fb0 = *(const bf16x8*)&Bs2[p][bpA + off];
      bf16x8 fb1 = *(const bf16x8*)&Bs2[p][bpB + off];
      acc[0][0] = __builtin_amdgcn_mfma_f32_16x16x32_bf16(a0, fb0, acc[0][0], 0, 0, 0);
      acc[1][0] = __builtin_amdgcn_mfma_f32_16x16x32_bf16(a1, fb0, acc[1][0], 0, 0, 0);
      acc[0][1] = __builtin_amdgcn_mfma_f32_16x16x32_bf16(a0, fb1, acc[0][1], 0, 0, 0);
      acc[1][1] = __builtin_amdgcn_mfma_f32_16x16x32_bf16(a1, fb1, acc[1][1], 0, 0, 0);
    }
    __syncthreads();
  }

#pragma unroll
  for (int ni = 0; ni < 2; ni++) {
    int col = nw + ni * 16 + fl;
    float bias = b2[g * OUT_ + col];
#pragma unroll
    for (int mi = 0; mi < 2; mi++) {
#pragma unroll
      for (int rg = 0; rg < 4; rg++) {
        int rl = m0 + mi * 16 + q * 4 + rg;
        if (row0 + rl < cnt) {
          y[(size_t)rows[rl] * OUT_ + col] = acc[mi][ni][rg] + bias;
        }
      }
    }
  }
}

extern "C" void kernel_launch(void* const* d_in, const int* in_sizes, int n_in,
                              void* d_out, int out_size, void* d_ws,
                              size_t ws_size, hipStream_t stream) {
  const float* x = (const float*)d_in[0];
  const int* gid = (const int*)d_in[1];
  const float* W1 = (const float*)d_in[2];
  const float* b1 = (const float*)d_in[3];
  const float* W2 = (const float*)d_in[4];
  const float* b2 = (const float*)d_in[5];
  float* y = (float*)d_out;

  int* meta = (int*)d_ws;                                             // 64 B
  int* perm = (int*)((char*)d_ws + 64);                               // 16 KB
  unsigned short* W1t = (unsigned short*)((char*)d_ws + (1u << 16));  // 8 MB
  unsigned short* W2t = (unsigned short*)((char*)d_ws + (16u << 20)); // 1 MB
  unsigned short* xb = (unsigned short*)((char*)d_ws + (24u << 20));  // 4 MB
  unsigned short* hb = (unsigned short*)((char*)d_ws + (32u << 20));  // 8 MB

  prep_kernel<<<5633, 256, 0, stream>>>(W1, W2, x, gid, W1t, W2t, xb, meta,
                                        perm);
  gemm1_kernel<<<MAXT32 * 16, 256, 0, stream>>>(xb, W1t, b1, meta, perm, hb);
  gemm2_kernel<<<MAXT64, 256, 0, stream>>>(hb, W2t, b2, meta, perm, y);
}

// Round 12
// 106.359 us; speedup vs baseline: 1.0762x; 1.0762x over previous
//
#include <hip/hip_runtime.h>
#include <hip/hip_bf16.h>

#define B_ 4096
#define G_ 8
#define IN_ 512
#define H_ 1024
#define OUT_ 64
#define MAXT64 72   // max 64-row tiles: 4096/64 + 8
#define MAXT32 136  // max 32-row tiles: 4096/32 + 8

typedef float f32x4 __attribute__((ext_vector_type(4)));
typedef __bf16 bf16x8 __attribute__((ext_vector_type(8)));
typedef unsigned short u16x8 __attribute__((ext_vector_type(8)));

__device__ inline unsigned short f2bf(float f) {
  unsigned int u = __builtin_bit_cast(unsigned int, f);
  u += 0x7fffu + ((u >> 16) & 1u);
  return (unsigned short)(u >> 16);
}

__device__ inline u16x8 pack8(float4 a, float4 b) {
  return u16x8{f2bf(a.x), f2bf(a.y), f2bf(a.z), f2bf(a.w),
               f2bf(b.x), f2bf(b.y), f2bf(b.z), f2bf(b.w)};
}

// Tile lookup for row-tile size 2^shift.
__device__ inline bool tile_lookup(const int* __restrict__ meta, int mt,
                                   int shift, int& g, int& row0, int& start,
                                   int& cnt) {
  int ts = 0;
  bool found = false;
#pragma unroll
  for (int gg = 0; gg < G_; gg++) {
    int s = meta[gg], e = meta[gg + 1];
    int T = (e - s + (1 << shift) - 1) >> shift;
    if (!found && mt >= ts && mt < ts + T) {
      g = gg;
      row0 = (mt - ts) << shift;
      start = s;
      cnt = e - s;
      found = true;
    }
    ts += T;
  }
  return found;
}

// ---------------------------------------------------------------------------
// prep (fused, all blocks independent):
//   [0,4096):    W1 [G][IN][H] f32 -> W1t [G][H][IN] bf16
//   [4096,4608): W2 [G][H][OUT] f32 -> W2t [G][OUT][H] bf16
//   [4608,5632): x f32 -> xb bf16
//   5632:        deterministic stable bucket (no atomics)
// ---------------------------------------------------------------------------
__global__ __launch_bounds__(256) void prep_kernel(
    const float* __restrict__ W1, const float* __restrict__ W2,
    const float* __restrict__ x, const int* __restrict__ gid,
    unsigned short* __restrict__ W1t, unsigned short* __restrict__ W2t,
    unsigned short* __restrict__ xb, int* __restrict__ meta,
    int* __restrict__ perm) {
  int b = blockIdx.x;
  int t = threadIdx.x;
  if (b < 4096) {
    __shared__ float tile[32][33];
    int h32 = b & 31, k32 = (b >> 5) & 15, g = b >> 9;
    int kl = t >> 3, nl = (t & 7) * 4;
    const float* src =
        W1 + ((size_t)g * IN_ + k32 * 32 + kl) * H_ + h32 * 32 + nl;
    float4 v = *(const float4*)src;
    tile[kl][nl + 0] = v.x;
    tile[kl][nl + 1] = v.y;
    tile[kl][nl + 2] = v.z;
    tile[kl][nl + 3] = v.w;
    __syncthreads();
    int nl2 = t >> 3, kl2 = (t & 7) * 4;
    ushort4 o;
    o.x = f2bf(tile[kl2 + 0][nl2]);
    o.y = f2bf(tile[kl2 + 1][nl2]);
    o.z = f2bf(tile[kl2 + 2][nl2]);
    o.w = f2bf(tile[kl2 + 3][nl2]);
    *(ushort4*)(W1t + ((size_t)g * H_ + h32 * 32 + nl2) * IN_ + k32 * 32 +
                kl2) = o;
  } else if (b < 4608) {
    __shared__ float tile2[32][33];
    int bb = b - 4096;
    int g = bb >> 6, k32 = (bb >> 1) & 31, n32 = bb & 1;
    int kl = t >> 3, nl = (t & 7) * 4;
    const float* src =
        W2 + ((size_t)g * H_ + k32 * 32 + kl) * OUT_ + n32 * 32 + nl;
    float4 v = *(const float4*)src;
    tile2[kl][nl + 0] = v.x;
    tile2[kl][nl + 1] = v.y;
    tile2[kl][nl + 2] = v.z;
    tile2[kl][nl + 3] = v.w;
    __syncthreads();
    int nl2 = t >> 3, kl2 = (t & 7) * 4;
    ushort4 o;
    o.x = f2bf(tile2[kl2 + 0][nl2]);
    o.y = f2bf(tile2[kl2 + 1][nl2]);
    o.z = f2bf(tile2[kl2 + 2][nl2]);
    o.w = f2bf(tile2[kl2 + 3][nl2]);
    *(ushort4*)(W2t + ((size_t)g * OUT_ + n32 * 32 + nl2) * H_ + k32 * 32 +
                kl2) = o;
  } else if (b < 5632) {
    int bb = b - 4608;
    size_t base = (size_t)bb * 2048 + t * 8;
    float4 v0 = *(const float4*)(x + base);
    float4 v1 = *(const float4*)(x + base + 4);
    *(u16x8*)(xb + base) = pack8(v0, v1);
  } else {
    __shared__ unsigned short lc[G_][256];
    __shared__ int offs_s[G_ + 1];
#pragma unroll
    for (int g = 0; g < G_; g++) lc[g][t] = 0;
    int myg[16];
    const int base = t * 16;
    __syncthreads();
#pragma unroll
    for (int j = 0; j < 16; j++) {
      myg[j] = gid[base + j];
      lc[myg[j]][t]++;
    }
    __syncthreads();
    {
      int g = t >> 5, k = t & 31;
      unsigned short pref[8];
      int s = 0;
#pragma unroll
      for (int j = 0; j < 8; j++) {
        pref[j] = (unsigned short)s;
        s += lc[g][8 * k + j];
      }
      int incl = s;
#pragma unroll
      for (int d = 1; d < 32; d <<= 1) {
        int o = __shfl_up(incl, d, 32);
        if (k >= d) incl += o;
      }
      int excl = incl - s;
      if (k == 31) offs_s[g + 1] = incl;
#pragma unroll
      for (int j = 0; j < 8; j++)
        lc[g][8 * k + j] = (unsigned short)(excl + pref[j]);
    }
    __syncthreads();
    if (t == 0) {
      int o = 0;
      for (int g = 0; g < G_; g++) {
        int c = offs_s[g + 1];
        offs_s[g] = o;
        meta[g] = o;
        o += c;
      }
      offs_s[G_] = o;
      meta[G_] = o;
    }
    __syncthreads();
    int cur[G_];
#pragma unroll
    for (int g = 0; g < G_; g++) cur[g] = offs_s[g] + (int)lc[g][t];
#pragma unroll
    for (int j = 0; j < 16; j++) {
      int g = myg[j];
      perm[cur[g]++] = base + j;
    }
  }
}

// ---------------------------------------------------------------------------
// gemm1: hb[start+r][:] = relu(xb[perm]·W1t[g] + b1[g]), bf16, permuted rows.
// 32x64 tile (2176 blocks, ~25 KB LDS), BK=64, 8 iters, 4 waves (2x2 of
// 16x32), double-buffered LDS, 1 barrier/iter, loads issued one iteration
// ahead. LDS chunk-XOR swizzle c^(r&7).  [R9 best: 107.8 us total]
// ---------------------------------------------------------------------------
__global__ __launch_bounds__(256) void gemm1_kernel(
    const unsigned short* __restrict__ xb,
    const unsigned short* __restrict__ W1t, const float* __restrict__ b1,
    const int* __restrict__ meta, const int* __restrict__ perm,
    unsigned short* __restrict__ hb) {
  int b = blockIdx.x;
  int mt = b >> 4, nt = b & 15;
  int g, row0, start, cnt;
  if (!tile_lookup(meta, mt, 5, g, row0, start, cnt)) return;
  int n0 = nt * 64;

  __shared__ __attribute__((aligned(16))) unsigned short As[2][32 * 64];
  __shared__ __attribute__((aligned(16))) unsigned short Bs[2][64 * 64];
  __shared__ int rows[32];

  int tid = threadIdx.x;
  int lane = tid & 63;
  int wv = tid >> 6;

  if (tid < 32) rows[tid] = perm[start + min(row0 + tid, cnt - 1)];
  __syncthreads();

  // A staging: thread t -> row r=t>>3, chunk cc=t&7 (16 B per iter)
  int r = tid >> 3, cc = tid & 7;
  const unsigned short* xsrc = xb + (size_t)rows[r] * IN_ + cc * 8;
  int aoff = r * 64 + ((cc ^ (r & 7)) << 3);

  // B staging: lane l of wave wv covers rows wv*16+(l>>3) and +8; source
  // chunk (l&7)^(row&7); LDS dest = lane-ordered base + lane*8 shorts.
  int brow0 = wv * 16 + (lane >> 3);
  int brow1 = brow0 + 8;
  int bsl = lane & 7;
  const unsigned short* bsrc0 = W1t + ((size_t)g * H_ + n0 + brow0) * IN_ +
                                ((bsl ^ (brow0 & 7)) << 3);
  const unsigned short* bsrc1 = W1t + ((size_t)g * H_ + n0 + brow1) * IN_ +
                                ((bsl ^ (brow1 & 7)) << 3);
  int boff0 = wv * 1024 + lane * 8;
  int boff1 = wv * 1024 + 512 + lane * 8;

  // fragments: wave tile 16x32 (m-half x n-half)
  int fl = lane & 15, q = lane >> 4;
  int m0 = (wv >> 1) * 16, nw = (wv & 1) * 32;
  int apA = (m0 + fl) * 64;
  int bpA = (nw + fl) * 64;
  int bpB = (nw + 16 + fl) * 64;

  f32x4 acc[2];
  acc[0] = f32x4{0.f, 0.f, 0.f, 0.f};
  acc[1] = f32x4{0.f, 0.f, 0.f, 0.f};

  // prologue: L0 -> buf0; issue L1
  u16x8 av = *(const u16x8*)(xsrc + 0);
  u16x8 bw0 = *(const u16x8*)(bsrc0 + 0);
  u16x8 bw1 = *(const u16x8*)(bsrc1 + 0);
  *(u16x8*)&As[0][aoff] = av;
  *(u16x8*)&Bs[0][boff0] = bw0;
  *(u16x8*)&Bs[0][boff1] = bw1;
  av = *(const u16x8*)(xsrc + 64);
  bw0 = *(const u16x8*)(bsrc0 + 64);
  bw1 = *(const u16x8*)(bsrc1 + 64);
  __syncthreads();  // buf0 visible; L1 loads remain in flight

  for (int it = 0; it < 8; it++) {
    int p = it & 1;
    if (it < 7) {  // commit L_{it+1} regs to the other buffer
      *(u16x8*)&As[p ^ 1][aoff] = av;
      *(u16x8*)&Bs[p ^ 1][boff0] = bw0;
      *(u16x8*)&Bs[p ^ 1][boff1] = bw1;
    }
    if (it < 6) {  // issue L_{it+2}, in flight for a full iteration
      int kn = (it + 2) * 64;
      av = *(const u16x8*)(xsrc + kn);
      bw0 = *(const u16x8*)(bsrc0 + kn);
      bw1 = *(const u16x8*)(bsrc1 + kn);
    }
#pragma unroll
    for (int s = 0; s < 2; s++) {
      int off = (((s << 2) + q) ^ (fl & 7)) << 3;
      bf16x8 a0 = *(const bf16x8*)&As[p][apA + off];
      bf16x8 fb0 = *(const bf16x8*)&Bs[p][bpA + off];
      bf16x8 fb1 = *(const bf16x8*)&Bs[p][bpB + off];
      acc[0] = __builtin_amdgcn_mfma_f32_16x16x32_bf16(a0, fb0, acc[0], 0, 0, 0);
      acc[1] = __builtin_amdgcn_mfma_f32_16x16x32_bf16(a0, fb1, acc[1], 0, 0, 0);
    }
    __syncthreads();  // one barrier/iter
  }

#pragma unroll
  for (int ni = 0; ni < 2; ni++) {
    int col = n0 + nw + ni * 16 + fl;
    float bias = b1[g * H_ + col];
#pragma unroll
    for (int rg = 0; rg < 4; rg++) {
      int rl = m0 + q * 4 + rg;
      if (row0 + rl < cnt) {
        float v = fmaxf(acc[ni][rg] + bias, 0.f);
        hb[(size_t)(start + row0 + rl) * H_ + col] = f2bf(v);
      }
    }
  }
}

// ---------------------------------------------------------------------------
// gemm2: y[perm[r]] = hb[r]·W2t[g] + b2[g]. Full K=1024 (8 iters of BK=128),
// plain stores, deterministic, double-buffered (round-7 proven).
// ---------------------------------------------------------------------------
__global__ __launch_bounds__(256) void gemm2_kernel(
    const unsigned short* __restrict__ hb,
    const unsigned short* __restrict__ W2t, const float* __restrict__ b2,
    const int* __restrict__ meta, const int* __restrict__ perm,
    float* __restrict__ y) {
  int mt = blockIdx.x;
  int g, row0, start, cnt;
  if (!tile_lookup(meta, mt, 6, g, row0, start, cnt)) return;

  __shared__ __attribute__((aligned(16))) unsigned short As2[2][64 * 128];
  __shared__ __attribute__((aligned(16))) unsigned short Bs2[2][64 * 128];
  __shared__ int rows[64];

  int tid = threadIdx.x;
  int lane = tid & 63;
  int wv = tid >> 6;

  if (tid < 64) rows[tid] = perm[start + min(row0 + tid, cnt - 1)];

  int arow_in_op = lane >> 4;
  int asl = lane & 15;
  const unsigned short* asrc[4];
  int adst[4];
#pragma unroll
  for (int j = 0; j < 4; j++) {
    int row = wv * 16 + j * 4 + arow_in_op;
    int cs = asl ^ (row & 7);
    asrc[j] =
        hb + (size_t)(start + min(row0 + row, cnt - 1)) * H_ + (cs << 3);
    adst[j] = (wv * 16 + j * 4) * 128 + lane * 8;
  }

  int bn = tid >> 2, qd = tid & 3;
  const unsigned short* bsrc = W2t + ((size_t)g * OUT_ + bn) * H_ + qd * 32;
  int bdst[4];
#pragma unroll
  for (int j = 0; j < 4; j++) {
    int ch = 4 * qd + j;
    bdst[j] = bn * 128 + ((ch ^ (bn & 7)) << 3);
  }

  int fl = lane & 15, q = lane >> 4;
  int m0 = (wv >> 1) * 32, nw = (wv & 1) * 32;
  int apA = (m0 + fl) * 128;
  int apB = (m0 + 16 + fl) * 128;
  int bpA = (nw + fl) * 128;
  int bpB = (nw + 16 + fl) * 128;

  f32x4 acc[2][2];
#pragma unroll
  for (int i = 0; i < 2; i++)
#pragma unroll
    for (int j = 0; j < 2; j++) acc[i][j] = f32x4{0.f, 0.f, 0.f, 0.f};

  u16x8 av[4], bv[4];
#pragma unroll
  for (int j = 0; j < 4; j++) av[j] = *(const u16x8*)(asrc[j] + 0);
#pragma unroll
  for (int j = 0; j < 4; j++) bv[j] = *(const u16x8*)(bsrc + j * 8);
  __syncthreads();  // rows[] visible
#pragma unroll
  for (int j = 0; j < 4; j++) *(u16x8*)&As2[0][adst[j]] = av[j];
#pragma unroll
  for (int j = 0; j < 4; j++) *(u16x8*)&Bs2[0][bdst[j]] = bv[j];
#pragma unroll
  for (int j = 0; j < 4; j++) av[j] = *(const u16x8*)(asrc[j] + 128);
#pragma unroll
  for (int j = 0; j < 4; j++) bv[j] = *(const u16x8*)(bsrc + 128 + j * 8);
  __syncthreads();

  for (int it = 0; it < 8; it++) {
    int p = it & 1;
    if (it < 7) {
#pragma unroll
      for (int j = 0; j < 4; j++) *(u16x8*)&As2[p ^ 1][adst[j]] = av[j];
#pragma unroll
      for (int j = 0; j < 4; j++) *(u16x8*)&Bs2[p ^ 1][bdst[j]] = bv[j];
    }
    if (it < 6) {
      int kn = (it + 2) * 128;
#pragma unroll
      for (int j = 0; j < 4; j++) av[j] = *(const u16x8*)(asrc[j] + kn);
#pragma unroll
      for (int j = 0; j < 4; j++)
        bv[j] = *(const u16x8*)(bsrc + kn + j * 8);
    }
#pragma unroll
    for (int s = 0; s < 4; s++) {
      int off = (((s << 2) + q) ^ (fl & 7)) << 3;
      bf16x8 a0 = *(const bf16x8*)&As2[p][apA + off];
      bf16x8 a1 = *(const bf16x8*)&As2[p][apB + off];
      bf16x8 fb0 = *(const bf16x8*)&Bs2[p][bpA + off];
      bf16x8 fb1 = *(const bf16x8*)&Bs2[p][bpB + off];
      acc[0][0] = __builtin_amdgcn_mfma_f32_16x16x32_bf16(a0, fb0, acc[0][0], 0, 0, 0);
      acc[1][0] = __builtin_amdgcn_mfma_f32_16x16x32_bf16(a1, fb0, acc[1][0], 0, 0, 0);
      acc[0][1] = __builtin_amdgcn_mfma_f32_16x16x32_bf16(a0, fb1, acc[0][1], 0, 0, 0);
      acc[1][1] = __builtin_amdgcn_mfma_f32_16x16x32_bf16(a1, fb1, acc[1][1], 0, 0, 0);
    }
    __syncthreads();
  }

#pragma unroll
  for (int ni = 0; ni < 2; ni++) {
    int col = nw + ni * 16 + fl;
    float bias = b2[g * OUT_ + col];
#pragma unroll
    for (int mi = 0; mi < 2; mi++) {
#pragma unroll
      for (int rg = 0; rg < 4; rg++) {
        int rl = m0 + mi * 16 + q * 4 + rg;
        if (row0 + rl < cnt) {
          y[(size_t)rows[rl] * OUT_ + col] = acc[mi][ni][rg] + bias;
        }
      }
    }
  }
}

extern "C" void kernel_launch(void* const* d_in, const int* in_sizes, int n_in,
                              void* d_out, int out_size, void* d_ws,
                              size_t ws_size, hipStream_t stream) {
  const float* x = (const float*)d_in[0];
  const int* gid = (const int*)d_in[1];
  const float* W1 = (const float*)d_in[2];
  const float* b1 = (const float*)d_in[3];
  const float* W2 = (const float*)d_in[4];
  const float* b2 = (const float*)d_in[5];
  float* y = (float*)d_out;

  int* meta = (int*)d_ws;                                             // 64 B
  int* perm = (int*)((char*)d_ws + 64);                               // 16 KB
  unsigned short* W1t = (unsigned short*)((char*)d_ws + (1u << 16));  // 8 MB
  unsigned short* W2t = (unsigned short*)((char*)d_ws + (16u << 20)); // 1 MB
  unsigned short* xb = (unsigned short*)((char*)d_ws + (24u << 20));  // 4 MB
  unsigned short* hb = (unsigned short*)((char*)d_ws + (32u << 20));  // 8 MB

  prep_kernel<<<5633, 256, 0, stream>>>(W1, W2, x, gid, W1t, W2t, xb, meta,
                                        perm);
  gemm1_kernel<<<MAXT32 * 16, 256, 0, stream>>>(xb, W1t, b1, meta, perm, hb);
  gemm2_kernel<<<MAXT64, 256, 0, stream>>>(hb, W2t, b2, meta, perm, y);
}